// Round 1
// baseline (2851.285 us; speedup 1.0000x reference)
//
#include <hip/hip_runtime.h>

// GraphSAGE 2-layer encoder, fp32.
// out = relu(seg_mean(x[src],dst) @ w1l + b1l + x @ w1r)  -> h
// out =      seg_mean(h[src],dst) @ w2l + b2l + h @ w2r
// Trick: (seg_sum(h[src]) * inv_deg) @ W == seg_sum((h@W)[src]) * inv_deg
// so we transform first (dense GEMM), scatter-add transformed rows, and fuse
// the self-path GEMM + bias + scaling (+relu) into a finalize kernel.

#define DIM 64

// ---------------- degree ----------------
__global__ __launch_bounds__(256) void deg_kernel(const int* __restrict__ dst,
                                                  float* __restrict__ deg, int nE) {
    int e = blockIdx.x * 256 + threadIdx.x;
    if (e < nE) unsafeAtomicAdd(&deg[dst[e]], 1.0f);
}

// ---------------- Y = H @ W  (H: n x 64, W: 64 x 64) ----------------
// 64 rows per block, 256 threads: thread = (row r0 = t>>4, dim-group dg = t&15),
// 4 passes of 16 rows. W + 64 H rows staged in LDS.
__global__ __launch_bounds__(256) void gemm64(const float* __restrict__ H,
                                              const float* __restrict__ W,
                                              float* __restrict__ Y, int n) {
    __shared__ float ws[64 * 64];
    __shared__ float hs[64 * 68];   // pad 68 to spread banks across rows
    const int t = threadIdx.x;
    for (int i = t * 4; i < 4096; i += 1024)
        *(float4*)&ws[i] = *(const float4*)&W[i];
    const int base = blockIdx.x * 64;
    for (int p = 0; p < 4; ++p) {
        int idx = t + p * 256;          // float4 index 0..1023
        int r = idx >> 4, c4 = idx & 15;
        int row = base + r;
        if (row < n)
            *(float4*)&hs[r * 68 + c4 * 4] = *(const float4*)&H[row * 64 + c4 * 4];
    }
    __syncthreads();
    const int dg = t & 15;
    const int r0 = t >> 4;
    for (int pass = 0; pass < 4; ++pass) {
        const int r = r0 + pass * 16;
        const int row = base + r;
        const float* hrow = &hs[r * 68];
        float4 acc = {0.f, 0.f, 0.f, 0.f};
#pragma unroll
        for (int k = 0; k < 64; k += 4) {
            float4 hv = *(const float4*)&hrow[k];
            float4 w0 = *(const float4*)&ws[(k + 0) * 64 + dg * 4];
            float4 w1 = *(const float4*)&ws[(k + 1) * 64 + dg * 4];
            float4 w2 = *(const float4*)&ws[(k + 2) * 64 + dg * 4];
            float4 w3 = *(const float4*)&ws[(k + 3) * 64 + dg * 4];
            acc.x = fmaf(hv.x, w0.x, acc.x); acc.y = fmaf(hv.x, w0.y, acc.y);
            acc.z = fmaf(hv.x, w0.z, acc.z); acc.w = fmaf(hv.x, w0.w, acc.w);
            acc.x = fmaf(hv.y, w1.x, acc.x); acc.y = fmaf(hv.y, w1.y, acc.y);
            acc.z = fmaf(hv.y, w1.z, acc.z); acc.w = fmaf(hv.y, w1.w, acc.w);
            acc.x = fmaf(hv.z, w2.x, acc.x); acc.y = fmaf(hv.z, w2.y, acc.y);
            acc.z = fmaf(hv.z, w2.z, acc.z); acc.w = fmaf(hv.z, w2.w, acc.w);
            acc.x = fmaf(hv.w, w3.x, acc.x); acc.y = fmaf(hv.w, w3.y, acc.y);
            acc.z = fmaf(hv.w, w3.z, acc.z); acc.w = fmaf(hv.w, w3.w, acc.w);
        }
        if (row < n)
            *(float4*)&Y[row * 64 + dg * 4] = acc;
    }
}

// ---------------- scatter: agg[dst] += Y[src] ----------------
// 16 threads per edge, float4 gather + 4 scalar HW fp32 atomics each.
__global__ __launch_bounds__(256) void scatter_kernel(const float* __restrict__ Y,
                                                      const int* __restrict__ src,
                                                      const int* __restrict__ dst,
                                                      float* __restrict__ agg, int nE) {
    int tid = blockIdx.x * 256 + threadIdx.x;
    int e = tid >> 4;
    if (e >= nE) return;
    int l = tid & 15;
    int s = src[e];
    int d = dst[e];
    float4 v = *(const float4*)&Y[s * 64 + l * 4];
    float* p = &agg[d * 64 + l * 4];
    unsafeAtomicAdd(p + 0, v.x);
    unsafeAtomicAdd(p + 1, v.y);
    unsafeAtomicAdd(p + 2, v.z);
    unsafeAtomicAdd(p + 3, v.w);
}

// ---------------- finalize: out = act(agg*inv_deg + bias + H @ Wr) ----------------
template <bool RELU>
__global__ __launch_bounds__(256) void finalize_kernel(const float* __restrict__ agg,
                                                       const float* __restrict__ deg,
                                                       const float* __restrict__ bias,
                                                       const float* __restrict__ H,
                                                       const float* __restrict__ W,
                                                       float* __restrict__ out, int n) {
    __shared__ float ws[64 * 64];
    __shared__ float hs[64 * 68];
    __shared__ float bs[64];
    const int t = threadIdx.x;
    for (int i = t * 4; i < 4096; i += 1024)
        *(float4*)&ws[i] = *(const float4*)&W[i];
    if (t < 16) *(float4*)&bs[t * 4] = *(const float4*)&bias[t * 4];
    const int base = blockIdx.x * 64;
    for (int p = 0; p < 4; ++p) {
        int idx = t + p * 256;
        int r = idx >> 4, c4 = idx & 15;
        int row = base + r;
        if (row < n)
            *(float4*)&hs[r * 68 + c4 * 4] = *(const float4*)&H[row * 64 + c4 * 4];
    }
    __syncthreads();
    const int dg = t & 15;
    const int r0 = t >> 4;
    for (int pass = 0; pass < 4; ++pass) {
        const int r = r0 + pass * 16;
        const int row = base + r;
        const float* hrow = &hs[r * 68];
        float4 acc = {0.f, 0.f, 0.f, 0.f};
#pragma unroll
        for (int k = 0; k < 64; k += 4) {
            float4 hv = *(const float4*)&hrow[k];
            float4 w0 = *(const float4*)&ws[(k + 0) * 64 + dg * 4];
            float4 w1 = *(const float4*)&ws[(k + 1) * 64 + dg * 4];
            float4 w2 = *(const float4*)&ws[(k + 2) * 64 + dg * 4];
            float4 w3 = *(const float4*)&ws[(k + 3) * 64 + dg * 4];
            acc.x = fmaf(hv.x, w0.x, acc.x); acc.y = fmaf(hv.x, w0.y, acc.y);
            acc.z = fmaf(hv.x, w0.z, acc.z); acc.w = fmaf(hv.x, w0.w, acc.w);
            acc.x = fmaf(hv.y, w1.x, acc.x); acc.y = fmaf(hv.y, w1.y, acc.y);
            acc.z = fmaf(hv.y, w1.z, acc.z); acc.w = fmaf(hv.y, w1.w, acc.w);
            acc.x = fmaf(hv.z, w2.x, acc.x); acc.y = fmaf(hv.z, w2.y, acc.y);
            acc.z = fmaf(hv.z, w2.z, acc.z); acc.w = fmaf(hv.z, w2.w, acc.w);
            acc.x = fmaf(hv.w, w3.x, acc.x); acc.y = fmaf(hv.w, w3.y, acc.y);
            acc.z = fmaf(hv.w, w3.z, acc.z); acc.w = fmaf(hv.w, w3.w, acc.w);
        }
        if (row < n) {
            float inv = 1.0f / fmaxf(deg[row], 1.0f);
            float4 a4 = *(const float4*)&agg[row * 64 + dg * 4];
            float4 b4 = *(const float4*)&bs[dg * 4];
            float4 o;
            o.x = fmaf(a4.x, inv, b4.x) + acc.x;
            o.y = fmaf(a4.y, inv, b4.y) + acc.y;
            o.z = fmaf(a4.z, inv, b4.z) + acc.z;
            o.w = fmaf(a4.w, inv, b4.w) + acc.w;
            if (RELU) {
                o.x = fmaxf(o.x, 0.f); o.y = fmaxf(o.y, 0.f);
                o.z = fmaxf(o.z, 0.f); o.w = fmaxf(o.w, 0.f);
            }
            *(float4*)&out[row * 64 + dg * 4] = o;
        }
    }
}

extern "C" void kernel_launch(void* const* d_in, const int* in_sizes, int n_in,
                              void* d_out, int out_size, void* d_ws, size_t ws_size,
                              hipStream_t stream) {
    const float* x   = (const float*)d_in[0];
    const int*   ei  = (const int*)d_in[1];
    const float* w1l = (const float*)d_in[2];
    const float* b1l = (const float*)d_in[3];
    const float* w1r = (const float*)d_in[4];
    const float* w2l = (const float*)d_in[5];
    const float* b2l = (const float*)d_in[6];
    const float* w2r = (const float*)d_in[7];
    float* out = (float*)d_out;

    const int N = in_sizes[0] / DIM;   // 100000
    const int E = in_sizes[1] / 2;     // 1600000
    const int* src = ei;
    const int* dst = ei + E;

    // workspace layout (floats): deg[N] | A=y[N*64] | B=agg[N*64] | C=h[N*64]
    float* deg = (float*)d_ws;
    float* A = deg + N;
    float* B = A + (size_t)N * DIM;
    float* C = B + (size_t)N * DIM;

    const int gb = (N + 63) / 64;                   // gemm/finalize blocks
    const int sb = (E * 16 + 255) / 256;            // scatter blocks
    const size_t feat_bytes = (size_t)N * DIM * sizeof(float);

    hipMemsetAsync(deg, 0, N * sizeof(float), stream);
    deg_kernel<<<(E + 255) / 256, 256, 0, stream>>>(dst, deg, E);

    // ---- layer 1 ----
    gemm64<<<gb, 256, 0, stream>>>(x, w1l, A, N);
    hipMemsetAsync(B, 0, feat_bytes, stream);
    scatter_kernel<<<sb, 256, 0, stream>>>(A, src, dst, B, E);
    finalize_kernel<true><<<gb, 256, 0, stream>>>(B, deg, b1l, x, w1r, C, N);

    // ---- layer 2 ----
    gemm64<<<gb, 256, 0, stream>>>(C, w2l, A, N);
    hipMemsetAsync(B, 0, feat_bytes, stream);
    scatter_kernel<<<sb, 256, 0, stream>>>(A, src, dst, B, E);
    finalize_kernel<false><<<gb, 256, 0, stream>>>(B, deg, b2l, C, w2r, out, N);
}

// Round 2
// 1052.050 us; speedup vs baseline: 2.7102x; 2.7102x over previous
//
#include <hip/hip_runtime.h>

// GraphSAGE 2-layer encoder, fp32 — CSR-gather version.
// Round 1 was atomic-scatter bound (2x1288us of 2851us, 205M fp atomics each).
// Round 2: build CSR (sorted-by-dst src lists) on device once per call, then
// aggregate by pull-gather fused into the finalize kernel. Still uses the
// algebraic identity (seg_sum(h[src])*inv_deg)@W == seg_sum((h@W)[src])*inv_deg
// so the gather reads the already-transformed table Y.

#define DIM 64

// ---------------- CSR build ----------------
__global__ __launch_bounds__(256) void count_kernel(const int* __restrict__ dst,
                                                    int* __restrict__ cnt, int nE) {
    int e = blockIdx.x * 256 + threadIdx.x;
    if (e < nE) atomicAdd(&cnt[dst[e]], 1);
}

// per-block sums of 1024 counts
__global__ __launch_bounds__(256) void scan1_kernel(const int* __restrict__ cnt,
                                                    int* __restrict__ blk_sums, int n) {
    __shared__ int sh[256];
    const int t = threadIdx.x;
    const int base = blockIdx.x * 1024 + t * 4;
    int s = 0;
#pragma unroll
    for (int i = 0; i < 4; ++i) {
        int idx = base + i;
        if (idx < n) s += cnt[idx];
    }
    sh[t] = s;
    __syncthreads();
    for (int d = 1; d < 256; d <<= 1) {
        int v = (t >= d) ? sh[t - d] : 0;
        __syncthreads();
        sh[t] += v;
        __syncthreads();
    }
    if (t == 255) blk_sums[blockIdx.x] = sh[255];
}

// exclusive scan of (up to 256) block sums, in place
__global__ __launch_bounds__(256) void scan2_kernel(int* __restrict__ blk_sums, int nb) {
    __shared__ int sh[256];
    const int t = threadIdx.x;
    int v = (t < nb) ? blk_sums[t] : 0;
    sh[t] = v;
    __syncthreads();
    for (int d = 1; d < 256; d <<= 1) {
        int u = (t >= d) ? sh[t - d] : 0;
        __syncthreads();
        sh[t] += u;
        __syncthreads();
    }
    if (t < nb) blk_sums[t] = sh[t] - v;   // exclusive
}

// write exclusive row offsets: row_start[i] = blk_off + local exclusive scan
__global__ __launch_bounds__(256) void scan3_kernel(const int* __restrict__ cnt,
                                                    const int* __restrict__ blk_sums,
                                                    int* __restrict__ row_start, int n) {
    __shared__ int sh[256];
    const int t = threadIdx.x;
    const int base = blockIdx.x * 1024 + t * 4;
    int c[4];
    int s = 0;
#pragma unroll
    for (int i = 0; i < 4; ++i) {
        int idx = base + i;
        c[i] = (idx < n) ? cnt[idx] : 0;
        s += c[i];
    }
    sh[t] = s;
    __syncthreads();
    for (int d = 1; d < 256; d <<= 1) {
        int v = (t >= d) ? sh[t - d] : 0;
        __syncthreads();
        sh[t] += v;
        __syncthreads();
    }
    int off = blk_sums[blockIdx.x] + sh[t] - s;  // exclusive offset of this thread's 4
#pragma unroll
    for (int i = 0; i < 4; ++i) {
        int idx = base + i;
        if (idx < n) row_start[idx] = off;
        off += c[i];
    }
}

// scatter edges into CSR slots. After this, row_start[i] == row END;
// consumers use start = row_start[i] - cnt[i].
__global__ __launch_bounds__(256) void fill_kernel(const int* __restrict__ src,
                                                   const int* __restrict__ dst,
                                                   int* __restrict__ row_start,
                                                   int* __restrict__ sorted_src, int nE) {
    int e = blockIdx.x * 256 + threadIdx.x;
    if (e < nE) {
        int d = dst[e];
        int pos = atomicAdd(&row_start[d], 1);
        sorted_src[pos] = src[e];
    }
}

// ---------------- Y = H @ W  (H: n x 64, W: 64 x 64) ----------------
__global__ __launch_bounds__(256) void gemm64(const float* __restrict__ H,
                                              const float* __restrict__ W,
                                              float* __restrict__ Y, int n) {
    __shared__ float ws[64 * 64];
    __shared__ float hs[64 * 68];
    const int t = threadIdx.x;
    for (int i = t * 4; i < 4096; i += 1024)
        *(float4*)&ws[i] = *(const float4*)&W[i];
    const int base = blockIdx.x * 64;
    for (int p = 0; p < 4; ++p) {
        int idx = t + p * 256;
        int r = idx >> 4, c4 = idx & 15;
        int row = base + r;
        if (row < n)
            *(float4*)&hs[r * 68 + c4 * 4] = *(const float4*)&H[row * 64 + c4 * 4];
    }
    __syncthreads();
    const int dg = t & 15;
    const int r0 = t >> 4;
    for (int pass = 0; pass < 4; ++pass) {
        const int r = r0 + pass * 16;
        const int row = base + r;
        const float* hrow = &hs[r * 68];
        float4 acc = {0.f, 0.f, 0.f, 0.f};
#pragma unroll
        for (int k = 0; k < 64; k += 4) {
            float4 hv = *(const float4*)&hrow[k];
            float4 w0 = *(const float4*)&ws[(k + 0) * 64 + dg * 4];
            float4 w1 = *(const float4*)&ws[(k + 1) * 64 + dg * 4];
            float4 w2 = *(const float4*)&ws[(k + 2) * 64 + dg * 4];
            float4 w3 = *(const float4*)&ws[(k + 3) * 64 + dg * 4];
            acc.x = fmaf(hv.x, w0.x, acc.x); acc.y = fmaf(hv.x, w0.y, acc.y);
            acc.z = fmaf(hv.x, w0.z, acc.z); acc.w = fmaf(hv.x, w0.w, acc.w);
            acc.x = fmaf(hv.y, w1.x, acc.x); acc.y = fmaf(hv.y, w1.y, acc.y);
            acc.z = fmaf(hv.y, w1.z, acc.z); acc.w = fmaf(hv.y, w1.w, acc.w);
            acc.x = fmaf(hv.z, w2.x, acc.x); acc.y = fmaf(hv.z, w2.y, acc.y);
            acc.z = fmaf(hv.z, w2.z, acc.z); acc.w = fmaf(hv.z, w2.w, acc.w);
            acc.x = fmaf(hv.w, w3.x, acc.x); acc.y = fmaf(hv.w, w3.y, acc.y);
            acc.z = fmaf(hv.w, w3.z, acc.z); acc.w = fmaf(hv.w, w3.w, acc.w);
        }
        if (row < n)
            *(float4*)&Y[row * 64 + dg * 4] = acc;
    }
}

// ---- finalize: out = act( gather_mean(Y) + bias + H @ Wr ) ----
// GEMM part identical to gemm64; gather part pulls neighbor rows from Y via CSR.
template <bool RELU>
__global__ __launch_bounds__(256) void finalize_kernel(const float* __restrict__ Y,
                                                       const int* __restrict__ cnt,
                                                       const int* __restrict__ row_end,
                                                       const int* __restrict__ sorted_src,
                                                       const float* __restrict__ bias,
                                                       const float* __restrict__ H,
                                                       const float* __restrict__ W,
                                                       float* __restrict__ out, int n) {
    __shared__ float ws[64 * 64];
    __shared__ float hs[64 * 68];
    __shared__ float bs[64];
    const int t = threadIdx.x;
    for (int i = t * 4; i < 4096; i += 1024)
        *(float4*)&ws[i] = *(const float4*)&W[i];
    if (t < 16) *(float4*)&bs[t * 4] = *(const float4*)&bias[t * 4];
    const int base = blockIdx.x * 64;
    for (int p = 0; p < 4; ++p) {
        int idx = t + p * 256;
        int r = idx >> 4, c4 = idx & 15;
        int row = base + r;
        if (row < n)
            *(float4*)&hs[r * 68 + c4 * 4] = *(const float4*)&H[row * 64 + c4 * 4];
    }
    __syncthreads();
    const int dg = t & 15;
    const int r0 = t >> 4;
    for (int pass = 0; pass < 4; ++pass) {
        const int r = r0 + pass * 16;
        const int row = base + r;
        if (row >= n) continue;
        const float* hrow = &hs[r * 68];
        float4 acc = {0.f, 0.f, 0.f, 0.f};
#pragma unroll
        for (int k = 0; k < 64; k += 4) {
            float4 hv = *(const float4*)&hrow[k];
            float4 w0 = *(const float4*)&ws[(k + 0) * 64 + dg * 4];
            float4 w1 = *(const float4*)&ws[(k + 1) * 64 + dg * 4];
            float4 w2 = *(const float4*)&ws[(k + 2) * 64 + dg * 4];
            float4 w3 = *(const float4*)&ws[(k + 3) * 64 + dg * 4];
            acc.x = fmaf(hv.x, w0.x, acc.x); acc.y = fmaf(hv.x, w0.y, acc.y);
            acc.z = fmaf(hv.x, w0.z, acc.z); acc.w = fmaf(hv.x, w0.w, acc.w);
            acc.x = fmaf(hv.y, w1.x, acc.x); acc.y = fmaf(hv.y, w1.y, acc.y);
            acc.z = fmaf(hv.y, w1.z, acc.z); acc.w = fmaf(hv.y, w1.w, acc.w);
            acc.x = fmaf(hv.z, w2.x, acc.x); acc.y = fmaf(hv.z, w2.y, acc.y);
            acc.z = fmaf(hv.z, w2.z, acc.z); acc.w = fmaf(hv.z, w2.w, acc.w);
            acc.x = fmaf(hv.w, w3.x, acc.x); acc.y = fmaf(hv.w, w3.y, acc.y);
            acc.z = fmaf(hv.w, w3.z, acc.z); acc.w = fmaf(hv.w, w3.w, acc.w);
        }
        // ---- CSR gather of transformed neighbor rows ----
        const int c = cnt[row];
        const int start = row_end[row] - c;
        float4 sum = {0.f, 0.f, 0.f, 0.f};
        for (int j = 0; j < c; ++j) {
            int s = sorted_src[start + j];
            float4 v = *(const float4*)&Y[(size_t)s * 64 + dg * 4];
            sum.x += v.x; sum.y += v.y; sum.z += v.z; sum.w += v.w;
        }
        const float inv = 1.0f / fmaxf((float)c, 1.0f);
        float4 b4 = *(const float4*)&bs[dg * 4];
        float4 o;
        o.x = fmaf(sum.x, inv, b4.x) + acc.x;
        o.y = fmaf(sum.y, inv, b4.y) + acc.y;
        o.z = fmaf(sum.z, inv, b4.z) + acc.z;
        o.w = fmaf(sum.w, inv, b4.w) + acc.w;
        if (RELU) {
            o.x = fmaxf(o.x, 0.f); o.y = fmaxf(o.y, 0.f);
            o.z = fmaxf(o.z, 0.f); o.w = fmaxf(o.w, 0.f);
        }
        *(float4*)&out[(size_t)row * 64 + dg * 4] = o;
    }
}

extern "C" void kernel_launch(void* const* d_in, const int* in_sizes, int n_in,
                              void* d_out, int out_size, void* d_ws, size_t ws_size,
                              hipStream_t stream) {
    const float* x   = (const float*)d_in[0];
    const int*   ei  = (const int*)d_in[1];
    const float* w1l = (const float*)d_in[2];
    const float* b1l = (const float*)d_in[3];
    const float* w1r = (const float*)d_in[4];
    const float* w2l = (const float*)d_in[5];
    const float* b2l = (const float*)d_in[6];
    const float* w2r = (const float*)d_in[7];
    float* out = (float*)d_out;

    const int N = in_sizes[0] / DIM;   // 100000
    const int E = in_sizes[1] / 2;     // 1600000
    const int* src = ei;
    const int* dst = ei + E;

    // workspace layout: cnt[N] | row_start[N] | blk_sums[256] | sorted_src[E] | A[N*64] | C[N*64]
    int* cnt = (int*)d_ws;
    int* row_start = cnt + N;
    int* blk_sums = row_start + N;
    int* sorted_src = blk_sums + 256;
    float* A = (float*)(sorted_src + E);
    float* C = A + (size_t)N * DIM;

    const int nb = (N + 1023) / 1024;           // scan blocks (<=256 assumed)
    const int eb = (E + 255) / 256;             // per-edge blocks
    const int gb = (N + 63) / 64;               // gemm/finalize blocks

    // ---- CSR build ----
    hipMemsetAsync(cnt, 0, N * sizeof(int), stream);
    count_kernel<<<eb, 256, 0, stream>>>(dst, cnt, E);
    scan1_kernel<<<nb, 256, 0, stream>>>(cnt, blk_sums, N);
    scan2_kernel<<<1, 256, 0, stream>>>(blk_sums, nb);
    scan3_kernel<<<nb, 256, 0, stream>>>(cnt, blk_sums, row_start, N);
    fill_kernel<<<eb, 256, 0, stream>>>(src, dst, row_start, sorted_src, E);
    // row_start now holds row END offsets.

    // ---- layer 1 ----
    gemm64<<<gb, 256, 0, stream>>>(x, w1l, A, N);
    finalize_kernel<true><<<gb, 256, 0, stream>>>(A, cnt, row_start, sorted_src,
                                                  b1l, x, w1r, C, N);
    // ---- layer 2 ----
    gemm64<<<gb, 256, 0, stream>>>(C, w2l, A, N);
    finalize_kernel<false><<<gb, 256, 0, stream>>>(A, cnt, row_start, sorted_src,
                                                   b2l, C, w2r, out, N);
}

// Round 3
// 458.785 us; speedup vs baseline: 6.2149x; 2.2931x over previous
//
#include <hip/hip_runtime.h>

// GraphSAGE 2-layer encoder, fp32 — CSR gather split from GEMM.
// R2 postmortem: fused finalize was latency-bound (VGPR 172 -> 2 waves/SIMD,
// occupancy 9.6%, serial dependent-load gather). R3: dual_gemm (VALU-bound,
// computes H@Wl and H@Wr+bias in one H pass) + lightweight high-occupancy
// gather_combine (4-way MLP unroll, fused mean+self+relu epilogue).

#define DIM 64

__device__ inline void fma4(float4& acc, float s, const float4 w) {
    acc.x = fmaf(s, w.x, acc.x); acc.y = fmaf(s, w.y, acc.y);
    acc.z = fmaf(s, w.z, acc.z); acc.w = fmaf(s, w.w, acc.w);
}

// ---------------- CSR build ----------------
__global__ __launch_bounds__(256) void count_kernel(const int* __restrict__ dst,
                                                    int* __restrict__ cnt, int nE) {
    int e = blockIdx.x * 256 + threadIdx.x;
    if (e < nE) atomicAdd(&cnt[dst[e]], 1);
}

__global__ __launch_bounds__(256) void scan1_kernel(const int* __restrict__ cnt,
                                                    int* __restrict__ blk_sums, int n) {
    __shared__ int sh[256];
    const int t = threadIdx.x;
    const int base = blockIdx.x * 1024 + t * 4;
    int s = 0;
#pragma unroll
    for (int i = 0; i < 4; ++i) {
        int idx = base + i;
        if (idx < n) s += cnt[idx];
    }
    sh[t] = s;
    __syncthreads();
    for (int d = 1; d < 256; d <<= 1) {
        int v = (t >= d) ? sh[t - d] : 0;
        __syncthreads();
        sh[t] += v;
        __syncthreads();
    }
    if (t == 255) blk_sums[blockIdx.x] = sh[255];
}

__global__ __launch_bounds__(256) void scan2_kernel(int* __restrict__ blk_sums, int nb) {
    __shared__ int sh[256];
    const int t = threadIdx.x;
    int v = (t < nb) ? blk_sums[t] : 0;
    sh[t] = v;
    __syncthreads();
    for (int d = 1; d < 256; d <<= 1) {
        int u = (t >= d) ? sh[t - d] : 0;
        __syncthreads();
        sh[t] += u;
        __syncthreads();
    }
    if (t < nb) blk_sums[t] = sh[t] - v;   // exclusive
}

__global__ __launch_bounds__(256) void scan3_kernel(const int* __restrict__ cnt,
                                                    const int* __restrict__ blk_sums,
                                                    int* __restrict__ row_start, int n) {
    __shared__ int sh[256];
    const int t = threadIdx.x;
    const int base = blockIdx.x * 1024 + t * 4;
    int c[4];
    int s = 0;
#pragma unroll
    for (int i = 0; i < 4; ++i) {
        int idx = base + i;
        c[i] = (idx < n) ? cnt[idx] : 0;
        s += c[i];
    }
    sh[t] = s;
    __syncthreads();
    for (int d = 1; d < 256; d <<= 1) {
        int v = (t >= d) ? sh[t - d] : 0;
        __syncthreads();
        sh[t] += v;
        __syncthreads();
    }
    int off = blk_sums[blockIdx.x] + sh[t] - s;
#pragma unroll
    for (int i = 0; i < 4; ++i) {
        int idx = base + i;
        if (idx < n) row_start[idx] = off;
        off += c[i];
    }
}

// After fill, row_start[i] == row END; start = end - cnt[i].
__global__ __launch_bounds__(256) void fill_kernel(const int* __restrict__ src,
                                                   const int* __restrict__ dst,
                                                   int* __restrict__ row_start,
                                                   int* __restrict__ sorted_src, int nE) {
    int e = blockIdx.x * 256 + threadIdx.x;
    if (e < nE) {
        int d = dst[e];
        int pos = atomicAdd(&row_start[d], 1);
        sorted_src[pos] = src[e];
    }
}

// ---- dual GEMM: A = H@Wl ; D = H@Wr + bias  (one pass over H) ----
// 64 rows/block, 256 threads: thread = (dg = t&15, r0 = t>>4), owns 4 rows
// (r0 + 16p). Each W fragment load is reused across 4 rows -> VALU-bound.
__global__ __launch_bounds__(256) void dual_gemm(const float* __restrict__ H,
                                                 const float* __restrict__ Wl,
                                                 const float* __restrict__ Wr,
                                                 const float* __restrict__ bias,
                                                 float* __restrict__ A,
                                                 float* __restrict__ Dbuf, int n) {
    __shared__ float wsl[4096];
    __shared__ float wsr[4096];
    __shared__ float hs[64 * 68];
    __shared__ float bs[64];
    const int t = threadIdx.x;
    for (int i = t * 4; i < 4096; i += 1024) {
        *(float4*)&wsl[i] = *(const float4*)&Wl[i];
        *(float4*)&wsr[i] = *(const float4*)&Wr[i];
    }
    if (t < 16) *(float4*)&bs[t * 4] = *(const float4*)&bias[t * 4];
    const int base = blockIdx.x * 64;
    for (int p = 0; p < 4; ++p) {
        int idx = t + p * 256;
        int r = idx >> 4, c4 = idx & 15;
        int row = base + r;
        if (row < n)
            *(float4*)&hs[r * 68 + c4 * 4] = *(const float4*)&H[(size_t)row * 64 + c4 * 4];
    }
    __syncthreads();
    const int dg = t & 15;
    const int r0 = t >> 4;
    float4 accl[4] = {{0,0,0,0},{0,0,0,0},{0,0,0,0},{0,0,0,0}};
    float4 accr[4] = {{0,0,0,0},{0,0,0,0},{0,0,0,0},{0,0,0,0}};
#pragma unroll 4
    for (int kq = 0; kq < 16; ++kq) {
        float4 wl[4], wr[4];
#pragma unroll
        for (int i = 0; i < 4; ++i) {
            wl[i] = *(const float4*)&wsl[(kq * 4 + i) * 64 + dg * 4];
            wr[i] = *(const float4*)&wsr[(kq * 4 + i) * 64 + dg * 4];
        }
#pragma unroll
        for (int p = 0; p < 4; ++p) {
            float4 hv = *(const float4*)&hs[(r0 + p * 16) * 68 + kq * 4];
            fma4(accl[p], hv.x, wl[0]); fma4(accl[p], hv.y, wl[1]);
            fma4(accl[p], hv.z, wl[2]); fma4(accl[p], hv.w, wl[3]);
            fma4(accr[p], hv.x, wr[0]); fma4(accr[p], hv.y, wr[1]);
            fma4(accr[p], hv.z, wr[2]); fma4(accr[p], hv.w, wr[3]);
        }
    }
    float4 b4 = *(const float4*)&bs[dg * 4];
#pragma unroll
    for (int p = 0; p < 4; ++p) {
        int row = base + r0 + p * 16;
        if (row < n) {
            *(float4*)&A[(size_t)row * 64 + dg * 4] = accl[p];
            float4 d;
            d.x = accr[p].x + b4.x; d.y = accr[p].y + b4.y;
            d.z = accr[p].z + b4.z; d.w = accr[p].w + b4.w;
            *(float4*)&Dbuf[(size_t)row * 64 + dg * 4] = d;
        }
    }
}

// ---- gather + combine: out = act( mean_{s in N(row)} Y[s] + D[row] ) ----
// 16 threads/row, 16 rows/block. Tiny VGPR footprint -> high occupancy;
// 4-way unrolled neighbor loop for memory-level parallelism.
template <bool RELU>
__global__ __launch_bounds__(256) void gather_combine(const float* __restrict__ Y,
                                                      const float* __restrict__ Dbuf,
                                                      const int* __restrict__ cnt,
                                                      const int* __restrict__ row_end,
                                                      const int* __restrict__ sorted_src,
                                                      float* __restrict__ out, int n) {
    const int t = threadIdx.x;
    const int row = blockIdx.x * 16 + (t >> 4);
    if (row >= n) return;
    const int dg = t & 15;
    const int c = cnt[row];
    const int* sp = sorted_src + (row_end[row] - c);
    float4 sum = {0.f, 0.f, 0.f, 0.f};
    int j = 0;
    for (; j + 4 <= c; j += 4) {
        int s0 = sp[j + 0], s1 = sp[j + 1], s2 = sp[j + 2], s3 = sp[j + 3];
        float4 v0 = *(const float4*)&Y[(size_t)s0 * 64 + dg * 4];
        float4 v1 = *(const float4*)&Y[(size_t)s1 * 64 + dg * 4];
        float4 v2 = *(const float4*)&Y[(size_t)s2 * 64 + dg * 4];
        float4 v3 = *(const float4*)&Y[(size_t)s3 * 64 + dg * 4];
        sum.x += (v0.x + v1.x) + (v2.x + v3.x);
        sum.y += (v0.y + v1.y) + (v2.y + v3.y);
        sum.z += (v0.z + v1.z) + (v2.z + v3.z);
        sum.w += (v0.w + v1.w) + (v2.w + v3.w);
    }
    for (; j < c; ++j) {
        int s = sp[j];
        float4 v = *(const float4*)&Y[(size_t)s * 64 + dg * 4];
        sum.x += v.x; sum.y += v.y; sum.z += v.z; sum.w += v.w;
    }
    const float inv = 1.0f / fmaxf((float)c, 1.0f);
    float4 d4 = *(const float4*)&Dbuf[(size_t)row * 64 + dg * 4];
    float4 o;
    o.x = fmaf(sum.x, inv, d4.x);
    o.y = fmaf(sum.y, inv, d4.y);
    o.z = fmaf(sum.z, inv, d4.z);
    o.w = fmaf(sum.w, inv, d4.w);
    if (RELU) {
        o.x = fmaxf(o.x, 0.f); o.y = fmaxf(o.y, 0.f);
        o.z = fmaxf(o.z, 0.f); o.w = fmaxf(o.w, 0.f);
    }
    *(float4*)&out[(size_t)row * 64 + dg * 4] = o;
}

extern "C" void kernel_launch(void* const* d_in, const int* in_sizes, int n_in,
                              void* d_out, int out_size, void* d_ws, size_t ws_size,
                              hipStream_t stream) {
    const float* x   = (const float*)d_in[0];
    const int*   ei  = (const int*)d_in[1];
    const float* w1l = (const float*)d_in[2];
    const float* b1l = (const float*)d_in[3];
    const float* w1r = (const float*)d_in[4];
    const float* w2l = (const float*)d_in[5];
    const float* b2l = (const float*)d_in[6];
    const float* w2r = (const float*)d_in[7];
    float* out = (float*)d_out;

    const int N = in_sizes[0] / DIM;   // 100000
    const int E = in_sizes[1] / 2;     // 1600000
    const int* src = ei;
    const int* dst = ei + E;

    // ws: cnt[N] | row_start[N] | blk_sums[256] | sorted_src[E] | A[N*64] | D[N*64]
    int* cnt = (int*)d_ws;
    int* row_start = cnt + N;
    int* blk_sums = row_start + N;
    int* sorted_src = blk_sums + 256;
    float* A = (float*)(sorted_src + E);
    float* D = A + (size_t)N * DIM;
    float* h1 = out;                    // layer-1 output reuses d_out as scratch

    const int nb = (N + 1023) / 1024;
    const int eb = (E + 255) / 256;
    const int gb = (N + 63) / 64;       // dual_gemm blocks
    const int cb = (N + 15) / 16;       // gather blocks

    // ---- CSR build ----
    hipMemsetAsync(cnt, 0, N * sizeof(int), stream);
    count_kernel<<<eb, 256, 0, stream>>>(dst, cnt, E);
    scan1_kernel<<<nb, 256, 0, stream>>>(cnt, blk_sums, N);
    scan2_kernel<<<1, 256, 0, stream>>>(blk_sums, nb);
    scan3_kernel<<<nb, 256, 0, stream>>>(cnt, blk_sums, row_start, N);
    fill_kernel<<<eb, 256, 0, stream>>>(src, dst, row_start, sorted_src, E);

    // ---- layer 1 ----
    dual_gemm<<<gb, 256, 0, stream>>>(x, w1l, w1r, b1l, A, D, N);
    gather_combine<true><<<cb, 256, 0, stream>>>(A, D, cnt, row_start, sorted_src, h1, N);

    // ---- layer 2 ----
    dual_gemm<<<gb, 256, 0, stream>>>(h1, w2l, w2r, b2l, A, D, N);
    gather_combine<false><<<cb, 256, 0, stream>>>(A, D, cnt, row_start, sorted_src, out, N);
}